// Round 6
// baseline (485.929 us; speedup 1.0000x reference)
//
#include <hip/hip_runtime.h>
#include <hip/hip_bf16.h>

typedef __attribute__((ext_vector_type(8))) short short8;
typedef __attribute__((ext_vector_type(4))) short short4v;
typedef __attribute__((ext_vector_type(4))) float f32x4;

// ---------- helpers ----------
__device__ __forceinline__ short f2bf(float f) {
    union { float f; unsigned u; } v; v.f = f;
    unsigned r = v.u + 0x7FFF + ((v.u >> 16) & 1);   // RNE
    return (short)(r >> 16);
}

__device__ __forceinline__ void gll16(const short* g, short* l) {
    __builtin_amdgcn_global_load_lds(
        (const __attribute__((address_space(1))) void*)g,
        (__attribute__((address_space(3))) void*)l, 16, 0, 0);
}

// sizes
#define NE 4
#define CC 384
#define CO 1152
#define TT 8
#define NN 197
#define NB 32
#define BT 256
#define MOEW_ELEMS 5308416   // 4*1152*384*3
#define W_ELEMS    442368    // 1152*384

// ---------------------------------------------------------------
// P0: prep — rf, Y (cls windows, bf16), convert moe_w & weight to bf16
// ---------------------------------------------------------------
__global__ __launch_bounds__(256) void prep_kernel(
    const float* __restrict__ x, const float* __restrict__ rf_w,
    const float* __restrict__ rf_b, const float* __restrict__ moe_w,
    const float* __restrict__ weight,
    short* __restrict__ moeWb, short* __restrict__ Wb,
    short* __restrict__ Yb, float* __restrict__ rf)
{
    int blk = blockIdx.x, tid = threadIdx.x;
    if (blk < NB) {
        __shared__ float clsL[TT * CC];    // [t][c]
        __shared__ float pooled[CC];
        int b = blk;
        for (int flat = tid; flat < TT * CC; flat += 256) {
            int t = flat / CC, c = flat - t * CC;
            clsL[flat] = x[(size_t)(b * TT + t) * NN * CC + c];  // n = 0 (cls token)
        }
        __syncthreads();
        for (int c = tid; c < CC; c += 256) {
            float s = 0.f;
            #pragma unroll
            for (int t = 0; t < TT; t++) s += clsL[t * CC + c];
            pooled[c] = s * 0.125f;
        }
        for (int t = 0; t < TT; t++)
            for (int flat = tid; flat < CC * 3; flat += 256) {
                int c = flat / 3, k = flat - c * 3;
                int u = t + k - 1;
                float v = (u >= 0 && u < TT) ? clsL[u * CC + c] : 0.f;
                Yb[(size_t)(b * TT + t) * (CC * 3) + flat] = f2bf(v);
            }
        __syncthreads();
        int wave = tid >> 6, lane = tid & 63;
        float p = 0.f;
        for (int c = lane; c < CC; c += 64) p += pooled[c] * rf_w[wave * CC + c];
        #pragma unroll
        for (int off = 32; off; off >>= 1) p += __shfl_down(p, off, 64);
        if (lane == 0) rf[b * NE + wave] = p + rf_b[wave];
    } else {
        const long NU = (MOEW_ELEMS + W_ELEMS) / 4;   // float4 units
        long step = (long)(gridDim.x - NB) * 256;
        for (long unit = (long)(blk - NB) * 256 + tid; unit < NU; unit += step) {
            long idx = unit * 4;
            float4 v; short* dst;
            if (idx < MOEW_ELEMS) { v = *(const float4*)(moe_w + idx); dst = moeWb + idx; }
            else { long j = idx - MOEW_ELEMS; v = *(const float4*)(weight + j); dst = Wb + j; }
            short4v s;
            s.x = f2bf(v.x); s.y = f2bf(v.y); s.z = f2bf(v.z); s.w = f2bf(v.w);
            *(short4v*)dst = s;
        }
    }
}

// ---------------------------------------------------------------
// P1: P[4608][256] = moeWb[4608][1152] @ Yb[256][1152]^T   (bf16 MFMA)
// ---------------------------------------------------------------
__global__ __launch_bounds__(256) void gemm_P(
    const short* __restrict__ A, const short* __restrict__ B, float* __restrict__ P)
{
    __shared__ short A_lds[64 * 64];
    __shared__ short B_lds[64 * 64];
    int bm = blockIdx.x, bn = blockIdx.y, tid = threadIdx.x;
    int wave = tid >> 6, lane = tid & 63, l15 = lane & 15, lq = lane >> 4;
    f32x4 acc[4];
    #pragma unroll
    for (int j = 0; j < 4; j++) acc[j] = (f32x4){0.f, 0.f, 0.f, 0.f};

    for (int kk = 0; kk < 1152 / 64; kk++) {
        __syncthreads();
        #pragma unroll
        for (int j2 = 0; j2 < 2; j2++) {
            int flat = j2 * 256 + tid;
            int row = flat >> 3, seg = flat & 7;
            gll16(A + (size_t)(bm * 64 + row) * 1152 + kk * 64 + seg * 8, &A_lds[flat * 8]);
            gll16(B + (size_t)(bn * 64 + row) * 1152 + kk * 64 + seg * 8, &B_lds[flat * 8]);
        }
        __syncthreads();
        #pragma unroll
        for (int ks = 0; ks < 2; ks++) {
            short8 a = *(short8*)&A_lds[(wave * 16 + l15) * 64 + ks * 32 + lq * 8];
            #pragma unroll
            for (int j = 0; j < 4; j++) {
                short8 bfr = *(short8*)&B_lds[(j * 16 + l15) * 64 + ks * 32 + lq * 8];
                acc[j] = __builtin_amdgcn_mfma_f32_16x16x32_bf16(a, bfr, acc[j], 0, 0, 0);
            }
        }
    }
    #pragma unroll
    for (int j = 0; j < 4; j++)
        #pragma unroll
        for (int reg = 0; reg < 4; reg++) {
            int row = bm * 64 + wave * 16 + lq * 4 + reg;   // eo
            int col = bn * 64 + j * 16 + l15;               // bt
            P[(size_t)row * 256 + col] = acc[j][reg];
        }
}

// ---------------------------------------------------------------
// P2: r_ws[bt][o] = 1 + sum_e rf[b][e]*(P[e*1152+o][bt] + moe_b[e][o])
// ---------------------------------------------------------------
__global__ __launch_bounds__(256) void combine_kernel(
    const float* __restrict__ P, const float* __restrict__ rf,
    const float* __restrict__ moe_b, float* __restrict__ r_ws)
{
    __shared__ float rf_l[NB * NE];
    int o = blockIdx.x, tid = threadIdx.x;
    if (tid < NB * NE) rf_l[tid] = rf[tid];
    __syncthreads();
    int b = tid >> 3;
    float acc = 1.0f;
    #pragma unroll
    for (int e = 0; e < NE; e++)
        acc += rf_l[b * NE + e] * (P[(size_t)(e * CO + o) * 256 + tid] + moe_b[e * CO + o]);
    r_ws[(size_t)tid * CO + o] = acc;
}

// ---------------------------------------------------------------
// Main (FUSED, BK=32, 8-wave blocks):
// out[bt][o][n] = sum_c W[o][c]*(x[bt][n][c]*r[bt][brC+c]) + bias[o]*r[bt][o]
//
// R5 post-mortem: counted-vmcnt == __syncthreads (null) -> drain was never
// the stall. Real limiter: REGISTER-capped occupancy. acc[2][7] = 56 AGPRs
// + 64 arch VGPRs = 120 unified/wave -> 4 waves/SIMD -> 4 blocks/CU
// (= measured 40% occupancy); 12 barriers/block then serialize per-wave
// L2/L3 latency tails. Fix: 512-thread / 8-wave blocks, wave owns 16
// o-rows -> acc[7] = 28 AGPR, staging halves (1 row/thread). Unified
// ~80/wave -> 6 waves/SIMD -> 3 blocks x 8 waves = 24 waves/CU (+87% TLP).
// Same tiles/swizzles (conflict-free, 0 in R4/R5), 1 barrier/iter.
// ---------------------------------------------------------------
__global__ __launch_bounds__(512) void main_gemm_fused(
    const float* __restrict__ x, const short* __restrict__ Wb,
    const float* __restrict__ r_ws, const float* __restrict__ bias,
    float* __restrict__ out)
{
    __shared__ short A_lds[2][128 * 32];   // 16 KB
    __shared__ short B_lds[2][112 * 32];   // 14 KB

    int g = blockIdx.x;
    int u = g & 7, w2 = g >> 3;
    int mt = w2 % 9;
    int pq = u + 8 * (w2 / 9);    // [0,512) ; 9 mt-blocks of one (bt,nt) share an XCD
    int bt = pq >> 1, nt = pq & 1;
    int tid = threadIdx.x;
    int br = mt / 3;

    const short* Abase = Wb + (size_t)(mt * 128) * CC;

    int wave = tid >> 6, lane = tid & 63, l15 = lane & 15, lq = lane >> 4;
    int oct = tid & 3;            // source octet (8 floats) within the 32-col tile
    int rbase = tid >> 2;         // B row [0,128); stagers cover [0,112)
    bool stager = (tid < 448);    // waves 0-6 stage B; wave 7 skips (uniform)

    // per-thread source pointers
    const float* xbase = x + ((size_t)bt * NN + nt * 112) * CC + oct * 8;
    const float* rbp   = r_ws + (size_t)bt * CO + br * CC + oct * 8;

    f32x4 acc[7];
    #pragma unroll
    for (int j = 0; j < 7; j++) acc[j] = (f32x4){0.f, 0.f, 0.f, 0.f};

    float4 xr0, xr1;     // staged x: one row, 8 floats
    float4 rr0, rr1;     // r octet for this K-tile

    // ---- prefetch tile t: r octet + x row (zero-filled for pad rows)
    auto prefetch = [&](int t) {
        if (stager) {
            rr0 = *(const float4*)(rbp + t * 32);
            rr1 = *(const float4*)(rbp + t * 32 + 4);
            float4 z = {0.f, 0.f, 0.f, 0.f};
            xr0 = z; xr1 = z;
            if (nt * 112 + rbase < NN) {
                const float* p = xbase + (size_t)rbase * CC + t * 32;
                xr0 = *(const float4*)p;
                xr1 = *(const float4*)(p + 4);
            }
        }
    };
    // ---- issue A tile t into buffer buf (1 gll16/thread, source-swizzled)
    auto issueA = [&](int t, int buf) {
        int row = tid >> 2, ss = tid & 3;
        int seg = ss ^ ((row >> 1) & 3);
        gll16(Abase + (size_t)row * CC + t * 32 + seg * 8, &A_lds[buf][tid * 8]);
    };
    // ---- stage B(t) from regs into LDS buf (scale + cvt + swizzled ds_write)
    auto stageB = [&](int pb) {
        if (stager) {
            int ss = oct ^ ((rbase >> 1) & 3);
            short8 s;
            s[0] = f2bf(xr0.x * rr0.x); s[1] = f2bf(xr0.y * rr0.y);
            s[2] = f2bf(xr0.z * rr0.z); s[3] = f2bf(xr0.w * rr0.w);
            s[4] = f2bf(xr1.x * rr1.x); s[5] = f2bf(xr1.y * rr1.y);
            s[6] = f2bf(xr1.z * rr1.z); s[7] = f2bf(xr1.w * rr1.w);
            *(short8*)&B_lds[pb][rbase * 32 + ss * 8] = s;
        }
    };
    // ---- compute tile in buf pb (7 MFMA; wave owns o-rows [wave*16, wave*16+16))
    auto compute = [&](int pb) {
        int sx = lq ^ ((l15 >> 1) & 3);   // swizzled segment for this lane
        short8 a = *(short8*)&A_lds[pb][(wave * 16 + l15) * 32 + sx * 8];
        #pragma unroll
        for (int j = 0; j < 7; j++) {
            short8 bfr = *(short8*)&B_lds[pb][(j * 16 + l15) * 32 + sx * 8];
            acc[j] = __builtin_amdgcn_mfma_f32_16x16x32_bf16(a, bfr, acc[j], 0, 0, 0);
        }
    };

    // prologue
    prefetch(0);
    issueA(0, 0);

    for (int t = 0; t < 12; t++) {
        int pb = t & 1;
        stageB(pb);            // waits x(t) regs; A(t) drained by the barrier below
        __syncthreads();       // B(t)+A(t) visible; buffer handoff
        if (t < 11) {          // next-tile loads hide under compute(t)
            prefetch(t + 1);
            issueA(t + 1, pb ^ 1);
        }
        compute(pb);
    }

    size_t outbase = (size_t)bt * (CO * NN);
    #pragma unroll
    for (int reg = 0; reg < 4; reg++) {
        int o = mt * 128 + wave * 16 + lq * 4 + reg;
        float bo = bias[o] * r_ws[(size_t)bt * CO + o];
        #pragma unroll
        for (int j = 0; j < 7; j++) {
            int n = nt * 112 + j * 16 + l15;
            if (n < NN) out[outbase + (size_t)o * NN + n] = acc[j][reg] + bo;
        }
    }
}

// ---------------------------------------------------------------
extern "C" void kernel_launch(void* const* d_in, const int* in_sizes, int n_in,
                              void* d_out, int out_size, void* d_ws, size_t ws_size,
                              hipStream_t stream) {
    const float* x      = (const float*)d_in[0];
    const float* rf_w   = (const float*)d_in[1];
    const float* rf_b   = (const float*)d_in[2];
    const float* moe_w  = (const float*)d_in[3];
    const float* moe_b  = (const float*)d_in[4];
    const float* weight = (const float*)d_in[5];
    const float* bias   = (const float*)d_in[6];
    float* out = (float*)d_out;

    char* ws = (char*)d_ws;
    short* Wb    = (short*)(ws + 0);            //    884,736 B
    short* moeWb = (short*)(ws + 884736);       // 10,616,832 B
    short* Yb    = (short*)(ws + 11501568);     //    589,824 B
    float* rf    = (float*)(ws + 12091392);     //        512 B
    float* P     = (float*)(ws + 12091904);     //  4,718,592 B
    float* r_ws  = (float*)(ws + 16810496);     //  1,179,648 B -> total ~18 MB

    prep_kernel<<<512, 256, 0, stream>>>(x, rf_w, rf_b, moe_w, weight, moeWb, Wb, Yb, rf);
    gemm_P<<<dim3(72, 4), 256, 0, stream>>>(moeWb, Yb, P);
    combine_kernel<<<1152, 256, 0, stream>>>(P, rf, moe_b, r_ws);
    main_gemm_fused<<<4608, 512, 0, stream>>>(x, Wb, r_ws, bias, out);
}

// Round 7
// 449.324 us; speedup vs baseline: 1.0815x; 1.0815x over previous
//
#include <hip/hip_runtime.h>
#include <hip/hip_bf16.h>

typedef __attribute__((ext_vector_type(8))) short short8;
typedef __attribute__((ext_vector_type(4))) short short4v;
typedef __attribute__((ext_vector_type(4))) float f32x4;

// ---------- helpers ----------
__device__ __forceinline__ short f2bf(float f) {
    union { float f; unsigned u; } v; v.f = f;
    unsigned r = v.u + 0x7FFF + ((v.u >> 16) & 1);   // RNE
    return (short)(r >> 16);
}

// HW RNE pack of 2 f32 -> 2 bf16 in one u32 (lo=src0, hi=src1).
// Bit-identical to f2bf for all finite inputs; 1 VALU op instead of ~8.
__device__ __forceinline__ unsigned cvtpk(float lo, float hi) {
    unsigned r;
    asm("v_cvt_pk_bf16_f32 %0, %1, %2" : "=v"(r) : "v"(lo), "v"(hi));
    return r;
}

__device__ __forceinline__ void gll16(const short* g, short* l) {
    __builtin_amdgcn_global_load_lds(
        (const __attribute__((address_space(1))) void*)g,
        (__attribute__((address_space(3))) void*)l, 16, 0, 0);
}

// sizes
#define NE 4
#define CC 384
#define CO 1152
#define TT 8
#define NN 197
#define NB 32
#define BT 256
#define KS 3                 // gemm_P split-K slices (18 tiles = 3 x 6)
#define MOEW_ELEMS 5308416   // 4*1152*384*3
#define W_ELEMS    442368    // 1152*384

// ---------------------------------------------------------------
// P0: prep — rf, Y (cls windows, bf16), convert moe_w & weight to bf16
// ---------------------------------------------------------------
__global__ __launch_bounds__(256) void prep_kernel(
    const float* __restrict__ x, const float* __restrict__ rf_w,
    const float* __restrict__ rf_b, const float* __restrict__ moe_w,
    const float* __restrict__ weight,
    short* __restrict__ moeWb, short* __restrict__ Wb,
    short* __restrict__ Yb, float* __restrict__ rf)
{
    int blk = blockIdx.x, tid = threadIdx.x;
    if (blk < NB) {
        __shared__ float clsL[TT * CC];    // [t][c]
        __shared__ float pooled[CC];
        int b = blk;
        for (int flat = tid; flat < TT * CC; flat += 256) {
            int t = flat / CC, c = flat - t * CC;
            clsL[flat] = x[(size_t)(b * TT + t) * NN * CC + c];  // n = 0 (cls token)
        }
        __syncthreads();
        for (int c = tid; c < CC; c += 256) {
            float s = 0.f;
            #pragma unroll
            for (int t = 0; t < TT; t++) s += clsL[t * CC + c];
            pooled[c] = s * 0.125f;
        }
        for (int t = 0; t < TT; t++)
            for (int flat = tid; flat < CC * 3; flat += 256) {
                int c = flat / 3, k = flat - c * 3;
                int u = t + k - 1;
                float v = (u >= 0 && u < TT) ? clsL[u * CC + c] : 0.f;
                Yb[(size_t)(b * TT + t) * (CC * 3) + flat] = f2bf(v);
            }
        __syncthreads();
        int wave = tid >> 6, lane = tid & 63;
        float p = 0.f;
        for (int c = lane; c < CC; c += 64) p += pooled[c] * rf_w[wave * CC + c];
        #pragma unroll
        for (int off = 32; off; off >>= 1) p += __shfl_down(p, off, 64);
        if (lane == 0) rf[b * NE + wave] = p + rf_b[wave];
    } else {
        const long NU = (MOEW_ELEMS + W_ELEMS) / 4;   // float4 units
        long step = (long)(gridDim.x - NB) * 256;
        for (long unit = (long)(blk - NB) * 256 + tid; unit < NU; unit += step) {
            long idx = unit * 4;
            float4 v; short* dst;
            if (idx < MOEW_ELEMS) { v = *(const float4*)(moe_w + idx); dst = moeWb + idx; }
            else { long j = idx - MOEW_ELEMS; v = *(const float4*)(weight + j); dst = Wb + j; }
            int2 s;
            s.x = (int)cvtpk(v.x, v.y);
            s.y = (int)cvtpk(v.z, v.w);
            *(int2*)dst = s;
        }
    }
}

// ---------------------------------------------------------------
// P1 (split-K): P[z][4608][256] = moeWb[.][z*384:(z+1)*384] @ Yb[.][same]^T
// grid (72, 4, 3) — 864 blocks (~3.4/CU) vs 288 (1.1/CU) before.
// ---------------------------------------------------------------
__global__ __launch_bounds__(256) void gemm_P(
    const short* __restrict__ A, const short* __restrict__ B, float* __restrict__ P)
{
    __shared__ short A_lds[64 * 64];
    __shared__ short B_lds[64 * 64];
    int bm = blockIdx.x, bn = blockIdx.y, z = blockIdx.z, tid = threadIdx.x;
    int wave = tid >> 6, lane = tid & 63, l15 = lane & 15, lq = lane >> 4;
    f32x4 acc[4];
    #pragma unroll
    for (int j = 0; j < 4; j++) acc[j] = (f32x4){0.f, 0.f, 0.f, 0.f};

    for (int kk = z * 6; kk < z * 6 + 6; kk++) {
        __syncthreads();
        #pragma unroll
        for (int j2 = 0; j2 < 2; j2++) {
            int flat = j2 * 256 + tid;
            int row = flat >> 3, seg = flat & 7;
            gll16(A + (size_t)(bm * 64 + row) * 1152 + kk * 64 + seg * 8, &A_lds[flat * 8]);
            gll16(B + (size_t)(bn * 64 + row) * 1152 + kk * 64 + seg * 8, &B_lds[flat * 8]);
        }
        __syncthreads();
        #pragma unroll
        for (int ks = 0; ks < 2; ks++) {
            short8 a = *(short8*)&A_lds[(wave * 16 + l15) * 64 + ks * 32 + lq * 8];
            #pragma unroll
            for (int j = 0; j < 4; j++) {
                short8 bfr = *(short8*)&B_lds[(j * 16 + l15) * 64 + ks * 32 + lq * 8];
                acc[j] = __builtin_amdgcn_mfma_f32_16x16x32_bf16(a, bfr, acc[j], 0, 0, 0);
            }
        }
    }
    #pragma unroll
    for (int j = 0; j < 4; j++)
        #pragma unroll
        for (int reg = 0; reg < 4; reg++) {
            int row = bm * 64 + wave * 16 + lq * 4 + reg;   // eo
            int col = bn * 64 + j * 16 + l15;               // bt
            P[((size_t)z * 4608 + row) * 256 + col] = acc[j][reg];
        }
}

// ---------------------------------------------------------------
// P2: r_ws[bt][o] = 1 + sum_e rf[b][e]*(sum_z Pz[e*1152+o][bt] + moe_b[e][o])
// ---------------------------------------------------------------
__global__ __launch_bounds__(256) void combine_kernel(
    const float* __restrict__ P, const float* __restrict__ rf,
    const float* __restrict__ moe_b, float* __restrict__ r_ws)
{
    __shared__ float rf_l[NB * NE];
    int o = blockIdx.x, tid = threadIdx.x;
    if (tid < NB * NE) rf_l[tid] = rf[tid];
    __syncthreads();
    int b = tid >> 3;
    float acc = 1.0f;
    #pragma unroll
    for (int e = 0; e < NE; e++) {
        float s = moe_b[e * CO + o];
        #pragma unroll
        for (int z = 0; z < KS; z++)
            s += P[((size_t)z * 4608 + e * CO + o) * 256 + tid];
        acc += rf_l[b * NE + e] * s;
    }
    r_ws[(size_t)tid * CO + o] = acc;
}

// ---------------------------------------------------------------
// Main (FUSED, BK=32, R4 structure + cvt_pk staging):
// out[bt][o][n] = sum_c W[o][c]*(x[bt][n][c]*r[bt][brC+c]) + bias[o]*r[bt][o]
//
// R5/R6 nulls: counted-vmcnt == __syncthreads; 8-wave blocks regressed
// (barrier freq per MFMA doubled, B-reads duplicated 8x). R4 structure is
// the proven best (173 us). Remaining top pipe was VALU (23%) — 16 software
// f2bf per thread per tile on the stage critical path. Fix: HW
// v_cvt_pk_bf16_f32 (T12 recipe), 8 ops instead of ~64, bit-identical RNE.
// Swizzle f(row)=(row>>1)&3: exact 2-way (free) LDS aliasing (0 conflicts
// measured). No launch_bounds clamp (R3: forced VGPR=48 -> spill).
// ---------------------------------------------------------------
__global__ __launch_bounds__(256) void main_gemm_fused(
    const float* __restrict__ x, const short* __restrict__ Wb,
    const float* __restrict__ r_ws, const float* __restrict__ bias,
    float* __restrict__ out)
{
    __shared__ short A_lds[2][128 * 32];   // 16 KB
    __shared__ short B_lds[2][112 * 32];   // 14 KB

    int g = blockIdx.x;
    int u = g & 7, w2 = g >> 3;
    int mt = w2 % 9;
    int pq = u + 8 * (w2 / 9);    // [0,512) ; 9 mt-blocks of one (bt,nt) share an XCD
    int bt = pq >> 1, nt = pq & 1;
    int tid = threadIdx.x;
    int br = mt / 3;

    const short* Abase = Wb + (size_t)(mt * 128) * CC;

    int wave = tid >> 6, lane = tid & 63, l15 = lane & 15, lq = lane >> 4;
    int oct = tid & 3;            // source octet (8 floats) within the 32-col tile
    int rbase = tid >> 2;         // row base [0,64)

    // per-thread source pointers
    const float* xbase = x + ((size_t)bt * NN + nt * 112) * CC + oct * 8;
    const float* rbp   = r_ws + (size_t)bt * CO + br * CC + oct * 8;

    f32x4 acc[2][7];
    #pragma unroll
    for (int i = 0; i < 2; i++)
        #pragma unroll
        for (int j = 0; j < 7; j++) acc[i][j] = (f32x4){0.f, 0.f, 0.f, 0.f};

    float4 xr[4];        // staged x: 2 row-passes x 8 floats
    float4 rr0, rr1;     // r octet for this K-tile

    // ---- prefetch tile t: r octet + x rows (zero-filled for pad rows)
    auto prefetch = [&](int t) {
        rr0 = *(const float4*)(rbp + t * 32);
        rr1 = *(const float4*)(rbp + t * 32 + 4);
        #pragma unroll
        for (int j2 = 0; j2 < 2; j2++) {
            int row = j2 * 64 + rbase;
            float4 z = {0.f, 0.f, 0.f, 0.f};
            xr[2 * j2] = z; xr[2 * j2 + 1] = z;
            if ((j2 == 0 || rbase < 48) && nt * 112 + row < NN) {
                const float* p = xbase + (size_t)row * CC + t * 32;
                xr[2 * j2]     = *(const float4*)p;
                xr[2 * j2 + 1] = *(const float4*)(p + 4);
            }
        }
    };
    // ---- issue A tile t into buffer buf (gll16, source-swizzled -> linear LDS)
    auto issueA = [&](int t, int buf) {
        #pragma unroll
        for (int j2 = 0; j2 < 2; j2++) {
            int flat = j2 * 256 + tid;
            int row = flat >> 2, ss = flat & 3;
            int seg = ss ^ ((row >> 1) & 3);
            gll16(Abase + (size_t)row * CC + t * 32 + seg * 8, &A_lds[buf][flat * 8]);
        }
    };
    // ---- stage B(t): scale + HW pack-cvt + swizzled ds_write
    auto stageB = [&](int pb) {
        short* Bd = &B_lds[pb][0];
        #pragma unroll
        for (int j2 = 0; j2 < 2; j2++) {
            int row = j2 * 64 + rbase;
            if (j2 == 0 || rbase < 48) {         // row < 112 (wave-uniform guard)
                int ss = oct ^ ((row >> 1) & 3);
                float4 a = xr[2 * j2], b = xr[2 * j2 + 1];
                int4 s;
                s.x = (int)cvtpk(a.x * rr0.x, a.y * rr0.y);
                s.y = (int)cvtpk(a.z * rr0.z, a.w * rr0.w);
                s.z = (int)cvtpk(b.x * rr1.x, b.y * rr1.y);
                s.w = (int)cvtpk(b.z * rr1.z, b.w * rr1.w);
                *(int4*)&Bd[row * 32 + ss * 8] = s;
            }
        }
    };
    // ---- compute tile in buf pb (14 MFMA)
    auto compute = [&](int pb) {
        int sx = lq ^ ((l15 >> 1) & 3);   // swizzled segment for this lane
        short8 a0 = *(short8*)&A_lds[pb][(wave * 32      + l15) * 32 + sx * 8];
        short8 a1 = *(short8*)&A_lds[pb][(wave * 32 + 16 + l15) * 32 + sx * 8];
        #pragma unroll
        for (int j = 0; j < 7; j++) {
            short8 bfr = *(short8*)&B_lds[pb][(j * 16 + l15) * 32 + sx * 8];
            acc[0][j] = __builtin_amdgcn_mfma_f32_16x16x32_bf16(a0, bfr, acc[0][j], 0, 0, 0);
            acc[1][j] = __builtin_amdgcn_mfma_f32_16x16x32_bf16(a1, bfr, acc[1][j], 0, 0, 0);
        }
    };

    // prologue
    prefetch(0);
    issueA(0, 0);

    for (int t = 0; t < 12; t++) {
        int pb = t & 1;
        stageB(pb);            // waits x(t) regs; A(t) drained by the barrier below
        __syncthreads();       // B(t)+A(t) visible; buffer handoff
        if (t < 11) {          // next-tile loads hide under compute(t)
            prefetch(t + 1);
            issueA(t + 1, pb ^ 1);
        }
        compute(pb);
    }

    size_t outbase = (size_t)bt * (CO * NN);
    #pragma unroll
    for (int mi = 0; mi < 2; mi++)
        #pragma unroll
        for (int reg = 0; reg < 4; reg++) {
            int o = mt * 128 + wave * 32 + mi * 16 + lq * 4 + reg;
            float bo = bias[o] * r_ws[(size_t)bt * CO + o];
            #pragma unroll
            for (int j = 0; j < 7; j++) {
                int n = nt * 112 + j * 16 + l15;
                if (n < NN) out[outbase + (size_t)o * NN + n] = acc[mi][j][reg] + bo;
            }
        }
}

// ---------------------------------------------------------------
extern "C" void kernel_launch(void* const* d_in, const int* in_sizes, int n_in,
                              void* d_out, int out_size, void* d_ws, size_t ws_size,
                              hipStream_t stream) {
    const float* x      = (const float*)d_in[0];
    const float* rf_w   = (const float*)d_in[1];
    const float* rf_b   = (const float*)d_in[2];
    const float* moe_w  = (const float*)d_in[3];
    const float* moe_b  = (const float*)d_in[4];
    const float* weight = (const float*)d_in[5];
    const float* bias   = (const float*)d_in[6];
    float* out = (float*)d_out;

    char* ws = (char*)d_ws;
    short* Wb    = (short*)(ws + 0);            //    884,736 B
    short* moeWb = (short*)(ws + 884736);       // 10,616,832 B
    short* Yb    = (short*)(ws + 11501568);     //    589,824 B
    float* rf    = (float*)(ws + 12091392);     //        512 B
    float* P     = (float*)(ws + 12091904);     // 14,155,776 B (3 K-slices)
    float* r_ws  = (float*)(ws + 26247680);     //  1,179,648 B -> total ~27.4 MB

    prep_kernel<<<512, 256, 0, stream>>>(x, rf_w, rf_b, moe_w, weight, moeWb, Wb, Yb, rf);
    gemm_P<<<dim3(72, 4, KS), 256, 0, stream>>>(moeWb, Yb, P);
    combine_kernel<<<1152, 256, 0, stream>>>(P, rf, moe_b, r_ws);
    main_gemm_fused<<<4608, 256, 0, stream>>>(x, Wb, r_ws, bias, out);
}